// Round 1
// baseline (387.927 us; speedup 1.0000x reference)
//
#include <hip/hip_runtime.h>

// Problem constants: mixture/target/noise are (N, 2, C, T, F) float32.
#define Nn 4
#define Cc 8
#define Tt 256
#define Ff 513
#define TFs (Tt * Ff)          // 131328
#define NPAIR 36               // upper triangle of 8x8
#define TCHUNK 16
#define NCHUNK (Tt / TCHUNK)   // 16

// ws layout: phi[2][N][F][36][2] floats, then wconj[N][F][8] float2
#define PHI_FLOATS (2 * Nn * Ff * NPAIR * 2)   // 295488
#define PHI_BYTES  (PHI_FLOATS * 4)            // 1181952 (16B aligned)

// ---------------------------------------------------------------------------
// Stage 1: partial time-averaged covariances, accumulated via atomics.
// grid: (9 f-blocks, N, NCHUNK*2) block: 64 (lane = f within 64-wide window)
// phi[inp][n][f][p][ri] += sum_t s_c(t) * conj(s_d(t)) for pair p=(c<=d)
// ---------------------------------------------------------------------------
__global__ __launch_bounds__(64) void cov_partial(
    const float* __restrict__ target, const float* __restrict__ noise,
    float* __restrict__ phi)
{
    int f = blockIdx.x * 64 + threadIdx.x;
    int n = blockIdx.y;
    int z = blockIdx.z;
    int inp = z & 1;          // 0 = target, 1 = noise
    int chunk = z >> 1;
    if (f >= Ff) return;

    const float* src = (inp == 0) ? target : noise;
    // idx(n, ri, c, t, f) = ((n*2 + ri)*Cc + c)*TFs + t*Ff + f
    const float* base = src + (size_t)n * 2 * Cc * TFs + f;

    float accr[NPAIR], acci[NPAIR];
#pragma unroll
    for (int p = 0; p < NPAIR; ++p) { accr[p] = 0.f; acci[p] = 0.f; }

    int t0 = chunk * TCHUNK;
    for (int tt = 0; tt < TCHUNK; ++tt) {
        const float* bt = base + (size_t)(t0 + tt) * Ff;
        float re[Cc], im[Cc];
#pragma unroll
        for (int c = 0; c < Cc; ++c) {
            re[c] = bt[(size_t)c * TFs];
            im[c] = bt[(size_t)(Cc + c) * TFs];
        }
        int p = 0;
#pragma unroll
        for (int c = 0; c < Cc; ++c) {
#pragma unroll
            for (int d = c; d < Cc; ++d) {
                // s_c * conj(s_d)
                accr[p] += re[c] * re[d] + im[c] * im[d];
                acci[p] += im[c] * re[d] - re[c] * im[d];
                ++p;
            }
        }
    }

    float* dst = phi + (((size_t)inp * Nn + n) * Ff + f) * (NPAIR * 2);
#pragma unroll
    for (int p = 0; p < NPAIR; ++p) {
        atomicAdd(dst + p * 2 + 0, accr[p]);
        atomicAdd(dst + p * 2 + 1, acci[p]);
    }
}

// ---------------------------------------------------------------------------
// Stage 2: per (n,f): build phi_noise (+complex diag loading), invert via
// Gauss-Jordan w/ partial pivoting in LDS, compute trace(inv@phiT) and
// column ref of inv@phiT, store conj(W). grid: (F, N), block: 128
// ---------------------------------------------------------------------------
__global__ __launch_bounds__(128) void mvdr_weights(
    const float* __restrict__ phi, const int* __restrict__ ref_ptr,
    float2* __restrict__ wconj)
{
    int f = blockIdx.x;
    int n = blockIdx.y;
    int tid = threadIdx.x;

    __shared__ float2 A[8][16];   // [phiN | I] augmented
    __shared__ float2 PT[8][8];   // phi_target
    __shared__ float2 gcol[8], trp[8];
    __shared__ int piv;

    const float invT = 1.0f / (float)Tt;
    const float dl = 0.001f / 1.41421356237309515f;  // 0.001/sqrt(2)

    if (tid < 64) {
        int r = tid >> 3, c = tid & 7;
        int lo = r <= c ? r : c, hi = r <= c ? c : r;
        int p = lo * 8 - lo * (lo - 1) / 2 + (hi - lo);
        // noise covariance -> A[:, 0:8]
        const float* pn = phi + (((size_t)1 * Nn + n) * Ff + f) * 72 + p * 2;
        float pr = pn[0] * invT, pi = pn[1] * invT;
        if (r > c) pi = -pi;                 // Hermitian reconstruction
        if (r == c) { pr += dl; pi += dl; }  // complex diagonal loading
        A[r][c] = make_float2(pr, pi);
        A[r][8 + c] = make_float2(r == c ? 1.f : 0.f, 0.f);
        // target covariance
        const float* pt = phi + (((size_t)0 * Nn + n) * Ff + f) * 72 + p * 2;
        float qr = pt[0] * invT, qi = pt[1] * invT;
        if (r > c) qi = -qi;
        PT[r][c] = make_float2(qr, qi);
    }
    __syncthreads();

    int r = tid >> 4, col = tid & 15;
    for (int k = 0; k < 8; ++k) {
        if (tid == 0) {
            int best = k;
            float bm = A[k][k].x * A[k][k].x + A[k][k].y * A[k][k].y;
            for (int j = k + 1; j < 8; ++j) {
                float m = A[j][k].x * A[j][k].x + A[j][k].y * A[j][k].y;
                if (m > bm) { bm = m; best = j; }
            }
            piv = best;
        }
        __syncthreads();
        int pv_row = piv;
        if (pv_row != k && tid < 16) {
            float2 tmp = A[k][tid]; A[k][tid] = A[pv_row][tid]; A[pv_row][tid] = tmp;
        }
        __syncthreads();
        if (tid < 16) {
            // all 16 lanes are in wave 0; reads precede writes in program order
            float2 pv = A[k][k];
            float d = pv.x * pv.x + pv.y * pv.y;
            float2 ip = make_float2(pv.x / d, -pv.y / d);
            float2 a = A[k][tid];
            A[k][tid] = make_float2(a.x * ip.x - a.y * ip.y,
                                    a.x * ip.y + a.y * ip.x);
        }
        __syncthreads();
        // eliminate: row k is only read; each row written only by its own wave
        float2 factor = A[r][k];
        float2 akc = A[k][col];
        if (r != k) {
            float2 v = A[r][col];
            A[r][col] = make_float2(v.x - (factor.x * akc.x - factor.y * akc.y),
                                    v.y - (factor.x * akc.y + factor.y * akc.x));
        }
        __syncthreads();
    }

    int ref = *ref_ptr;
    if (tid < 8) {
        float2 g = make_float2(0.f, 0.f), tr = make_float2(0.f, 0.f);
#pragma unroll
        for (int d = 0; d < 8; ++d) {
            float2 iv = A[tid][8 + d];
            float2 b = PT[d][ref];
            g.x += iv.x * b.x - iv.y * b.y;
            g.y += iv.x * b.y + iv.y * b.x;
            float2 b2 = PT[d][tid];
            tr.x += iv.x * b2.x - iv.y * b2.y;
            tr.y += iv.x * b2.y + iv.y * b2.x;
        }
        gcol[tid] = g; trp[tid] = tr;
    }
    __syncthreads();
    if (tid < 8) {
        float lx = 0.f, ly = 0.f;
#pragma unroll
        for (int j = 0; j < 8; ++j) { lx += trp[j].x; ly += trp[j].y; }
        float den = lx * lx + ly * ly;
        float2 g = gcol[tid];
        float wx = (g.x * lx + g.y * ly) / den;   // W = g / l
        float wy = (g.y * lx - g.x * ly) / den;
        // store conj(W)
        wconj[((size_t)n * Ff + f) * 8 + tid] = make_float2(wx, -wy);
    }
}

// ---------------------------------------------------------------------------
// Stage 3: X_bf(n,t,f) = sum_c conj(W)(n,f,c) * y(n,c,t,f); write re/im.
// grid: N*T*F/256 = 2052 blocks of 256 (exact)
// ---------------------------------------------------------------------------
__global__ __launch_bounds__(256) void beamform(
    const float* __restrict__ y, const float2* __restrict__ wconj,
    float* __restrict__ out)
{
    int idx = blockIdx.x * 256 + threadIdx.x;   // < N*T*F = 525312
    int n = idx / TFs;
    int rem = idx - n * TFs;
    int t = rem / Ff;
    int f = rem - t * Ff;

    size_t base_re = (size_t)n * 2 * Cc * TFs + (size_t)t * Ff + f;
    size_t base_im = base_re + (size_t)Cc * TFs;
    const float2* w = wconj + ((size_t)n * Ff + f) * 8;

    float xr = 0.f, xi = 0.f;
#pragma unroll
    for (int c = 0; c < Cc; ++c) {
        float yre = y[base_re + (size_t)c * TFs];
        float yim = y[base_im + (size_t)c * TFs];
        float2 wc = w[c];
        xr += wc.x * yre - wc.y * yim;
        xi += wc.x * yim + wc.y * yre;
    }
    size_t ob = (size_t)n * 2 * TFs + (size_t)t * Ff + f;
    out[ob] = xr;           // real plane
    out[ob + TFs] = xi;     // imag plane
}

extern "C" void kernel_launch(void* const* d_in, const int* in_sizes, int n_in,
                              void* d_out, int out_size, void* d_ws, size_t ws_size,
                              hipStream_t stream) {
    const float* mixture = (const float*)d_in[0];
    const float* target  = (const float*)d_in[1];
    const float* noise   = (const float*)d_in[2];
    const int*   refp    = (const int*)d_in[3];
    float* out = (float*)d_out;

    float*  phi   = (float*)d_ws;
    float2* wconj = (float2*)((char*)d_ws + PHI_BYTES);

    // ws is poisoned 0xAA before every timed launch -> zero the accumulator
    hipMemsetAsync(d_ws, 0, PHI_BYTES, stream);

    cov_partial<<<dim3(9, Nn, NCHUNK * 2), 64, 0, stream>>>(target, noise, phi);
    mvdr_weights<<<dim3(Ff, Nn), 128, 0, stream>>>(phi, refp, wconj);
    beamform<<<dim3((Nn * TFs) / 256), 256, 0, stream>>>(mixture, wconj, out);
}

// Round 2
// 161.302 us; speedup vs baseline: 2.4050x; 2.4050x over previous
//
#include <hip/hip_runtime.h>

// mixture/target/noise: (N, 2, C, T, F) float32
#define Nn 4
#define Cc 8
#define Tt 256
#define Ff 513
#define TFs (Tt * Ff)      // 131328
#define NPAIR 36           // upper triangle of 8x8 Hermitian

// ---------------------------------------------------------------------------
// Stage 1: partial covariances, NO atomics, NO spills.
// Pair-group G handles rows {G, 7-G} of the Hermitian matrix (9 pairs).
// Partial layout: [inp][n][chunk][p][ri][f]  (f contiguous -> coalesced)
// ---------------------------------------------------------------------------
template <int G>
__device__ __forceinline__ void cov_body(const float* __restrict__ base,
                                         float* __restrict__ dst,
                                         int t0, int tchunk)
{
    constexpr int R2 = 7 - G;
    float ar[9], ai[9];
#pragma unroll
    for (int s = 0; s < 9; ++s) { ar[s] = 0.f; ai[s] = 0.f; }

    const float* bt = base + (size_t)t0 * Ff;
    for (int tt = 0; tt < tchunk; ++tt) {
        float re[8], im[8];
#pragma unroll
        for (int c = G; c < 8; ++c) {
            re[c] = bt[(size_t)c * TFs];
            im[c] = bt[(size_t)(Cc + c) * TFs];
        }
        int s = 0;
#pragma unroll
        for (int d = G; d < 8; ++d, ++s) {     // row G
            ar[s] += re[G] * re[d] + im[G] * im[d];
            ai[s] += im[G] * re[d] - re[G] * im[d];
        }
#pragma unroll
        for (int d = R2; d < 8; ++d, ++s) {    // row 7-G
            ar[s] += re[R2] * re[d] + im[R2] * im[d];
            ai[s] += im[R2] * re[d] - re[R2] * im[d];
        }
        bt += Ff;
    }

    int s = 0;
#pragma unroll
    for (int d = G; d < 8; ++d, ++s) {
        const int p = G * 8 - G * (G - 1) / 2 + (d - G);
        dst[(size_t)(p * 2 + 0) * Ff] = ar[s];
        dst[(size_t)(p * 2 + 1) * Ff] = ai[s];
    }
#pragma unroll
    for (int d = R2; d < 8; ++d, ++s) {
        const int p = R2 * 8 - R2 * (R2 - 1) / 2 + (d - R2);
        dst[(size_t)(p * 2 + 0) * Ff] = ar[s];
        dst[(size_t)(p * 2 + 1) * Ff] = ai[s];
    }
}

__global__ __launch_bounds__(64) void cov_partial(
    const float* __restrict__ target, const float* __restrict__ noise,
    float* __restrict__ partial, int nchunk, int tchunk)
{
    int f = blockIdx.x * 64 + threadIdx.x;
    if (f >= Ff) return;
    int n = blockIdx.y;
    int z = blockIdx.z;
    int g = z & 3;
    int inp = (z >> 2) & 1;
    int chunk = z >> 3;

    const float* src = inp ? noise : target;
    const float* base = src + (size_t)n * 2 * Cc * TFs + f;
    float* dst = partial +
        ((((size_t)inp * Nn + n) * nchunk + chunk) * (NPAIR * 2)) * Ff + f;
    int t0 = chunk * tchunk;

    switch (g) {
        case 0: cov_body<0>(base, dst, t0, tchunk); break;
        case 1: cov_body<1>(base, dst, t0, tchunk); break;
        case 2: cov_body<2>(base, dst, t0, tchunk); break;
        default: cov_body<3>(base, dst, t0, tchunk); break;
    }
}

// ---------------------------------------------------------------------------
// Stage 2: fused chunk-reduce + MVDR weights. grid (F, N), block 128.
// ---------------------------------------------------------------------------
__global__ __launch_bounds__(128) void mvdr_weights(
    const float* __restrict__ partial, const int* __restrict__ ref_ptr,
    float2* __restrict__ wconj, int nchunk)
{
    int f = blockIdx.x;
    int n = blockIdx.y;
    int tid = threadIdx.x;

    __shared__ float covT[72], covN[72];
    __shared__ float2 A[8][16];   // [phiN | I]
    __shared__ float2 PT[8][8];
    __shared__ float2 gcol[8], trp[8];
    __shared__ int piv;

    if (tid < 72) {
        float sT = 0.f, sN = 0.f;
        for (int ch = 0; ch < nchunk; ++ch) {
            size_t iT = ((((size_t)0 * Nn + n) * nchunk + ch) * 72 + tid) * Ff + f;
            size_t iN = ((((size_t)1 * Nn + n) * nchunk + ch) * 72 + tid) * Ff + f;
            sT += partial[iT];
            sN += partial[iN];
        }
        covT[tid] = sT;
        covN[tid] = sN;
    }
    __syncthreads();

    const float invT = 1.0f / (float)Tt;
    const float dl = 0.001f / 1.41421356237309515f;  // 0.001/sqrt(2)

    if (tid < 64) {
        int r = tid >> 3, c = tid & 7;
        int lo = r <= c ? r : c, hi = r <= c ? c : r;
        int p = lo * 8 - lo * (lo - 1) / 2 + (hi - lo);
        float pr = covN[2 * p] * invT, pi = covN[2 * p + 1] * invT;
        if (r > c) pi = -pi;                  // Hermitian reconstruction
        if (r == c) { pr += dl; pi += dl; }   // complex diagonal loading
        A[r][c] = make_float2(pr, pi);
        A[r][8 + c] = make_float2(r == c ? 1.f : 0.f, 0.f);
        float qr = covT[2 * p] * invT, qi = covT[2 * p + 1] * invT;
        if (r > c) qi = -qi;
        PT[r][c] = make_float2(qr, qi);
    }
    __syncthreads();

    int r = tid >> 4, col = tid & 15;
    for (int k = 0; k < 8; ++k) {
        if (tid == 0) {
            int best = k;
            float bm = A[k][k].x * A[k][k].x + A[k][k].y * A[k][k].y;
            for (int j = k + 1; j < 8; ++j) {
                float m = A[j][k].x * A[j][k].x + A[j][k].y * A[j][k].y;
                if (m > bm) { bm = m; best = j; }
            }
            piv = best;
        }
        __syncthreads();
        int pv_row = piv;
        if (pv_row != k && tid < 16) {
            float2 tmp = A[k][tid]; A[k][tid] = A[pv_row][tid]; A[pv_row][tid] = tmp;
        }
        __syncthreads();
        if (tid < 16) {
            float2 pv = A[k][k];
            float d = pv.x * pv.x + pv.y * pv.y;
            float2 ip = make_float2(pv.x / d, -pv.y / d);
            float2 a = A[k][tid];
            A[k][tid] = make_float2(a.x * ip.x - a.y * ip.y,
                                    a.x * ip.y + a.y * ip.x);
        }
        __syncthreads();
        float2 factor = A[r][k];
        float2 akc = A[k][col];
        if (r != k) {
            float2 v = A[r][col];
            A[r][col] = make_float2(v.x - (factor.x * akc.x - factor.y * akc.y),
                                    v.y - (factor.x * akc.y + factor.y * akc.x));
        }
        __syncthreads();
    }

    int ref = *ref_ptr;
    if (tid < 8) {
        float2 g = make_float2(0.f, 0.f), tr = make_float2(0.f, 0.f);
#pragma unroll
        for (int d = 0; d < 8; ++d) {
            float2 iv = A[tid][8 + d];
            float2 b = PT[d][ref];
            g.x += iv.x * b.x - iv.y * b.y;
            g.y += iv.x * b.y + iv.y * b.x;
            float2 b2 = PT[d][tid];
            tr.x += iv.x * b2.x - iv.y * b2.y;
            tr.y += iv.x * b2.y + iv.y * b2.x;
        }
        gcol[tid] = g; trp[tid] = tr;
    }
    __syncthreads();
    if (tid < 8) {
        float lx = 0.f, ly = 0.f;
#pragma unroll
        for (int j = 0; j < 8; ++j) { lx += trp[j].x; ly += trp[j].y; }
        float den = lx * lx + ly * ly;
        float2 g = gcol[tid];
        float wx = (g.x * lx + g.y * ly) / den;   // W = g / l
        float wy = (g.y * lx - g.x * ly) / den;
        wconj[((size_t)n * Ff + f) * 8 + tid] = make_float2(wx, -wy);  // conj(W)
    }
}

// ---------------------------------------------------------------------------
// Stage 3: X_bf(n,t,f) = sum_c conj(W)(n,f,c) * y(n,c,t,f)
// ---------------------------------------------------------------------------
__global__ __launch_bounds__(256) void beamform(
    const float* __restrict__ y, const float2* __restrict__ wconj,
    float* __restrict__ out)
{
    int idx = blockIdx.x * 256 + threadIdx.x;   // < N*T*F = 525312
    int n = idx / TFs;
    int rem = idx - n * TFs;
    int t = rem / Ff;
    int f = rem - t * Ff;

    size_t base_re = (size_t)n * 2 * Cc * TFs + (size_t)t * Ff + f;
    size_t base_im = base_re + (size_t)Cc * TFs;
    const float2* w = wconj + ((size_t)n * Ff + f) * 8;

    float xr = 0.f, xi = 0.f;
#pragma unroll
    for (int c = 0; c < Cc; ++c) {
        float yre = y[base_re + (size_t)c * TFs];
        float yim = y[base_im + (size_t)c * TFs];
        float2 wc = w[c];
        xr += wc.x * yre - wc.y * yim;
        xi += wc.x * yim + wc.y * yre;
    }
    size_t ob = (size_t)n * 2 * TFs + (size_t)t * Ff + f;
    out[ob] = xr;
    out[ob + TFs] = xi;
}

extern "C" void kernel_launch(void* const* d_in, const int* in_sizes, int n_in,
                              void* d_out, int out_size, void* d_ws, size_t ws_size,
                              hipStream_t stream) {
    const float* mixture = (const float*)d_in[0];
    const float* target  = (const float*)d_in[1];
    const float* noise   = (const float*)d_in[2];
    const int*   refp    = (const int*)d_in[3];
    float* out = (float*)d_out;

    const size_t wconj_bytes = (size_t)Nn * Ff * 8 * sizeof(float2);
    int nchunk = 8;
    while (nchunk > 1 &&
           (size_t)2 * Nn * nchunk * 72 * Ff * sizeof(float) + wconj_bytes > ws_size)
        nchunk >>= 1;
    int tchunk = Tt / nchunk;

    float*  partial = (float*)d_ws;
    float2* wconj = (float2*)((char*)d_ws +
                              (size_t)2 * Nn * nchunk * 72 * Ff * sizeof(float));

    cov_partial<<<dim3(9, Nn, nchunk * 8), 64, 0, stream>>>(
        target, noise, partial, nchunk, tchunk);
    mvdr_weights<<<dim3(Ff, Nn), 128, 0, stream>>>(partial, refp, wconj, nchunk);
    beamform<<<dim3((Nn * TFs) / 256), 256, 0, stream>>>(mixture, wconj, out);
}